// Round 8
// baseline (1096.500 us; speedup 1.0000x reference)
//
#include <hip/hip_runtime.h>

#define HID 256
#define TLEN 1024
#define BATCH 128

typedef _Float16 half2_t __attribute__((ext_vector_type(2)));

__device__ __forceinline__ float fexp2(float x) { return __builtin_amdgcn_exp2f(x); }
__device__ __forceinline__ float frcp(float x)  { return __builtin_amdgcn_rcpf(x); }
__device__ __forceinline__ float fast_sigmoid(float x) {
  return frcp(1.0f + fexp2(-1.442695040888963f * x));
}
__device__ __forceinline__ float fast_tanh(float x) {
  float e = fexp2(2.885390081777927f * x);
  return 1.0f - 2.0f * frcp(e + 1.0f);
}
__device__ __forceinline__ float dot2acc(half2_t a, half2_t b, float c) {
  return __builtin_amdgcn_fdot2(a, b, c, false);   // v_dot2_f32_f16
}

#if defined(__has_builtin) && __has_builtin(__builtin_amdgcn_sdot4)
#define SDOT4(a, b, c) __builtin_amdgcn_sdot4((int)(a), (int)(b), (c), false)
#else
__device__ __forceinline__ int SDOT4(int a, int b, int c) {
#pragma unroll
  for (int e = 0; e < 4; ++e)
    c += ((a << (24 - 8 * e)) >> 24) * ((b << (24 - 8 * e)) >> 24);
  return c;
}
#endif

// DPP helpers (VALU pipe; conventions verified empirically in R7:
// ctrl 0x10N => lane i reads lane i+N; 0xB1 = quad xor1; 0x4E = quad xor2)
#define DPP_ADD_F(var, ctrl, rmask)                                            \
  var += __builtin_bit_cast(float, __builtin_amdgcn_update_dpp(                \
      0, __builtin_bit_cast(int, var), (ctrl), (rmask), 0xf, true))
#define DPP_ADD_I(var, ctrl)                                                   \
  var += __builtin_amdgcn_update_dpp(0, (var), (ctrl), 0xf, 0xf, true)
#define DPP_MOV_I(dst, src, ctrl)                                              \
  dst = __builtin_amdgcn_update_dpp(0, (src), (ctrl), 0xf, 0xf, true)

__device__ __forceinline__ float wave_sum63(float p) {
  DPP_ADD_F(p, 0x111, 0xf);   // row_shr:1
  DPP_ADD_F(p, 0x112, 0xf);   // row_shr:2
  DPP_ADD_F(p, 0x114, 0xf);   // row_shr:4
  DPP_ADD_F(p, 0x118, 0xf);   // row_shr:8
  DPP_ADD_F(p, 0x142, 0xa);   // row_bcast:15
  DPP_ADD_F(p, 0x143, 0xc);   // row_bcast:31 -> lane63 has total
  return p;
}

// LDS-only barrier (leave global loads in flight)
#define LDS_BARRIER() asm volatile("s_waitcnt lgkmcnt(0)\n\ts_barrier" ::: "memory")

// ---- prep: per-row symmetric i8 quant of W_hh (768x256), packed for the
// R=6 layout: main thread t=(dgrp<<2)|q owns rows {g*256 + 2*dgrp + e} and
// k-blocks c=4i+q (16B each). wq[t*24 + (g*2+e)*4 + i] = block (row, c).
__global__ void quant_whh(const float* __restrict__ W_hh, uint4* __restrict__ wq,
                          float* __restrict__ scales) {
  const int r = blockIdx.x * 256 + threadIdx.x;   // 0..767
  if (r >= 768) return;
  const float* row = W_hh + (size_t)r * HID;
  float amax = 0.0f;
  for (int k = 0; k < HID; ++k) amax = fmaxf(amax, fabsf(row[k]));
  amax = fmaxf(amax, 1e-20f);
  scales[r] = amax / 127.0f;
  const float inv = 127.0f / amax;
  const int g = r >> 8, dd = r & 255;
  const int dgrp = dd >> 1, e = dd & 1;
  for (int c = 0; c < 16; ++c) {
    unsigned w[4];
#pragma unroll
    for (int u = 0; u < 4; ++u) {
      unsigned bb = 0;
#pragma unroll
      for (int ee = 0; ee < 4; ++ee) {
        int qv = (int)rintf(row[c * 16 + u * 4 + ee] * inv);
        bb |= (unsigned)(qv & 0xff) << (8 * ee);
      }
      w[u] = bb;
    }
    const int i = c >> 2, q = c & 3;
    wq[(size_t)(4 * dgrp + q) * 24 + (g * 2 + e) * 4 + i] =
        uint4{w[0], w[1], w[2], w[3]};
  }
}

// One block per batch element, 512 threads (8 waves, 2/SIMD).
// R=6 mapping: thread (dgrp=tid>>2, q=tid&3) owns dims {2dgrp, 2dgrp+1} for
// all 3 gates (6 rows), k-blocks {4i+q} (64 B of h). All weights register-
// resident as i8 (24 uint4 = 96 VGPRs; AGPR parking absorbs overflow — R7
// showed this is memory-traffic-free). DS per step: 32 h-broadcast
// ds_read_b128 + 8 b32 h-writes + red — ~3x less than R7's 96+ instr.
// Quad partials combine via DPP xor1/xor2; wave reduce via DPP row_shr chain.
__global__ __launch_bounds__(512, 1)
void momgru_persistent(const float* __restrict__ x,
                       const float* __restrict__ W_ih,
                       const float* __restrict__ b_ih,
                       const float* __restrict__ b_hh,
                       const float* __restrict__ Wb_x,
                       const float* __restrict__ Wb_h,
                       const float* __restrict__ b_beta,
                       const float* __restrict__ s_ptr,
                       const float* __restrict__ W_head,
                       const float* __restrict__ b_head,
                       const uint4* __restrict__ wq,
                       const float* __restrict__ scales,
                       float* __restrict__ out)  // [0,128) head, [128,128+B*T) betas
{
  const int b    = blockIdx.x;
  const int tid  = threadIdx.x;
  const int lane = tid & 63;
  const int wv   = tid >> 6;
  const int dgrp = tid >> 2;
  const int q    = tid & 3;
  const int d0   = 2 * dgrp, d1 = d0 + 1;

  __shared__ unsigned hbuf[2][HID / 4];   // 512 B: h as i8, double-buffered
  __shared__ float    red[2][8];          // per-wave hWb partials

  // ---- weights: 24 uint4, register/AGPR resident ----
  const uint4* wqt = wq + (size_t)tid * 24;
  uint4 w[24];
#pragma unroll
  for (int i = 0; i < 24; ++i) w[i] = wqt[i];

  // ---- per-thread constants (2 dims x 3 gates) ----
  const half2_t wih_r0 = half2_t{(_Float16)W_ih[2 * d0],             (_Float16)W_ih[2 * d0 + 1]};
  const half2_t wih_r1 = half2_t{(_Float16)W_ih[2 * d1],             (_Float16)W_ih[2 * d1 + 1]};
  const half2_t wih_z0 = half2_t{(_Float16)W_ih[2 * (HID + d0)],     (_Float16)W_ih[2 * (HID + d0) + 1]};
  const half2_t wih_z1 = half2_t{(_Float16)W_ih[2 * (HID + d1)],     (_Float16)W_ih[2 * (HID + d1) + 1]};
  const half2_t wih_n0 = half2_t{(_Float16)W_ih[2 * (2 * HID + d0)], (_Float16)W_ih[2 * (2 * HID + d0) + 1]};
  const half2_t wih_n1 = half2_t{(_Float16)W_ih[2 * (2 * HID + d1)], (_Float16)W_ih[2 * (2 * HID + d1) + 1]};
  const float bih_r0 = b_ih[d0], bih_r1 = b_ih[d1];
  const float bih_z0 = b_ih[HID + d0], bih_z1 = b_ih[HID + d1];
  const float bih_n0 = b_ih[2 * HID + d0], bih_n1 = b_ih[2 * HID + d1];
  const float bhh_r0 = b_hh[d0], bhh_r1 = b_hh[d1];
  const float bhh_z0 = b_hh[HID + d0], bhh_z1 = b_hh[HID + d1];
  const float bhh_n0 = b_hh[2 * HID + d0], bhh_n1 = b_hh[2 * HID + d1];
  const float sc_r0 = scales[d0] * (1.0f / 127.0f), sc_r1 = scales[d1] * (1.0f / 127.0f);
  const float sc_z0 = scales[HID + d0] * (1.0f / 127.0f), sc_z1 = scales[HID + d1] * (1.0f / 127.0f);
  const float sc_n0 = scales[2 * HID + d0] * (1.0f / 127.0f), sc_n1 = scales[2 * HID + d1] * (1.0f / 127.0f);
  const half2_t wbx2 = half2_t{(_Float16)Wb_x[0], (_Float16)Wb_x[1]};
  const float bbeta = b_beta[0], sv = s_ptr[0];
  const float wbh0 = Wb_h[d0], wbh1 = Wb_h[d1];
  const float wh0 = W_head[d0], wh1 = W_head[d1];

  // ---- init state ----
  if (tid < 128) reinterpret_cast<unsigned*>(hbuf)[tid] = 0u;
  float h0 = 0.0f, h1 = 0.0f;
  float vr0 = 0.0f, vr1 = 0.0f, vz0 = 0.0f, vz1 = 0.0f, vn0 = 0.0f, vn1 = 0.0f;
  float hWb = 0.0f;
  float* betas = out + BATCH;
  const float2* xg2 = reinterpret_cast<const float2*>(x + (size_t)b * TLEN * 2);
  float2 xv = xg2[0];
  __syncthreads();

  int cur = 0;
  for (int t = 0; t < TLEN; ++t) {
    const half2_t x2 = half2_t{(_Float16)xv.x, (_Float16)xv.y};
    xv = xg2[(t + 1 < TLEN) ? t + 1 : t];

    const float beta = fast_sigmoid(dot2acc(x2, wbx2, hWb + bbeta));
    vr0 = beta * vr0 + sv * dot2acc(x2, wih_r0, bih_r0);
    vr1 = beta * vr1 + sv * dot2acc(x2, wih_r1, bih_r1);
    vz0 = beta * vz0 + sv * dot2acc(x2, wih_z0, bih_z0);
    vz1 = beta * vz1 + sv * dot2acc(x2, wih_z1, bih_z1);
    vn0 = beta * vn0 + sv * dot2acc(x2, wih_n0, bih_n0);
    vn1 = beta * vn1 + sv * dot2acc(x2, wih_n1, bih_n1);

    // i8 matvec: 6 rows x this thread's 64-byte k-quarter (blocks 4i+q)
    int acc[6] = {0, 0, 0, 0, 0, 0};
    const int4* hb = reinterpret_cast<const int4*>(hbuf[cur]);
#pragma unroll
    for (int i = 0; i < 4; ++i) {
      const int4 hv = hb[4 * i + q];
#pragma unroll
      for (int rl = 0; rl < 6; ++rl) {
        const uint4 ww = w[rl * 4 + i];
        acc[rl] = SDOT4(hv.x, ww.x, acc[rl]);
        acc[rl] = SDOT4(hv.y, ww.y, acc[rl]);
        acc[rl] = SDOT4(hv.z, ww.z, acc[rl]);
        acc[rl] = SDOT4(hv.w, ww.w, acc[rl]);
      }
    }
#pragma unroll
    for (int rl = 0; rl < 6; ++rl) {
      DPP_ADD_I(acc[rl], 0xB1);   // quad xor1
      DPP_ADD_I(acc[rl], 0x4E);   // quad xor2 -> all 4 lanes have full sums
    }

    const float r0 = fast_sigmoid(vr0 + (float)acc[0] * sc_r0 + bhh_r0);
    const float r1 = fast_sigmoid(vr1 + (float)acc[1] * sc_r1 + bhh_r1);
    const float z0 = fast_sigmoid(vz0 + (float)acc[2] * sc_z0 + bhh_z0);
    const float z1 = fast_sigmoid(vz1 + (float)acc[3] * sc_z1 + bhh_z1);
    const float n0 = fast_tanh(vn0 + r0 * ((float)acc[4] * sc_n0 + bhh_n0));
    const float n1 = fast_tanh(vn1 + r1 * ((float)acc[5] * sc_n1 + bhh_n1));
    h0 = (1.0f - z0) * n0 + z0 * h0;
    h1 = (1.0f - z1) * n1 + z1 * h1;

    // quantize h -> i8; writer lane tid%8==0 packs dims 4m..4m+3
    const int nxt = cur ^ 1;
    const int qb0 = ((int)rintf(h0 * 127.0f)) & 0xff;
    const int qb1 = ((int)rintf(h1 * 127.0f)) & 0xff;
    const int q16 = qb0 | (qb1 << 8);
    int qhi;
    DPP_MOV_I(qhi, q16, 0x104);   // lane i <- lane i+4 (R7-verified)
    if ((tid & 7) == 0) hbuf[nxt][tid >> 3] = (unsigned)(q16 | (qhi << 16));

    // hWb partial -> per-wave DPP sum -> one LDS word per wave
    float p = (q == 0) ? h0 * wbh0 + h1 * wbh1 : 0.0f;
    p = wave_sum63(p);
    const int rb = t & 1;
    if (lane == 63) red[rb][wv] = p;
    if (tid == 63) betas[(size_t)b * TLEN + t] = beta;

    LDS_BARRIER();
    hWb = red[rb][0] + red[rb][1] + red[rb][2] + red[rb][3] +
          red[rb][4] + red[rb][5] + red[rb][6] + red[rb][7];
    cur = nxt;
  }

  // ---- head ----
  float hp = (q == 0) ? h0 * wh0 + h1 * wh1 : 0.0f;
  hp = wave_sum63(hp);
  if (lane == 63) red[0][wv] = hp;
  __syncthreads();
  if (tid == 0) {
    out[b] = red[0][0] + red[0][1] + red[0][2] + red[0][3] +
             red[0][4] + red[0][5] + red[0][6] + red[0][7] + b_head[0];
  }
}

extern "C" void kernel_launch(void* const* d_in, const int* in_sizes, int n_in,
                              void* d_out, int out_size, void* d_ws, size_t ws_size,
                              hipStream_t stream) {
  const float* x      = (const float*)d_in[0];
  const float* W_ih   = (const float*)d_in[1];
  const float* W_hh   = (const float*)d_in[2];
  const float* b_ih   = (const float*)d_in[3];
  const float* b_hh   = (const float*)d_in[4];
  const float* Wb_x   = (const float*)d_in[5];
  const float* Wb_h   = (const float*)d_in[6];
  const float* b_beta = (const float*)d_in[7];
  const float* s      = (const float*)d_in[8];
  const float* W_head = (const float*)d_in[9];
  const float* b_head = (const float*)d_in[10];
  float* out = (float*)d_out;

  uint4* wq     = (uint4*)d_ws;                              // 512*24*16 = 192 KB
  float* scales = (float*)((char*)d_ws + 512 * 24 * 16);     // +3 KB

  quant_whh<<<dim3(3), dim3(256), 0, stream>>>(W_hh, wq, scales);
  momgru_persistent<<<dim3(BATCH), dim3(512), 0, stream>>>(
      x, W_ih, b_ih, b_hh, Wb_x, Wb_h, b_beta, s, W_head, b_head,
      (const uint4*)wq, (const float*)scales, out);
}

// Round 10
// 960.933 us; speedup vs baseline: 1.1411x; 1.1411x over previous
//
#include <hip/hip_runtime.h>

#define HID 256
#define TLEN 1024
#define BATCH 128

typedef _Float16 half2_t __attribute__((ext_vector_type(2)));

__device__ __forceinline__ float fexp2(float x) { return __builtin_amdgcn_exp2f(x); }
__device__ __forceinline__ float frcp(float x)  { return __builtin_amdgcn_rcpf(x); }
__device__ __forceinline__ float fast_sigmoid(float x) {
  return frcp(1.0f + fexp2(-1.442695040888963f * x));
}
__device__ __forceinline__ float fast_tanh(float x) {
  float e = fexp2(2.885390081777927f * x);
  return 1.0f - 2.0f * frcp(e + 1.0f);
}
__device__ __forceinline__ float dot2acc(half2_t a, half2_t b, float c) {
  return __builtin_amdgcn_fdot2(a, b, c, false);   // v_dot2_f32_f16
}

#if defined(__has_builtin) && __has_builtin(__builtin_amdgcn_sdot4)
#define SDOT4(a, b, c) __builtin_amdgcn_sdot4((int)(a), (int)(b), (c), false)
#else
__device__ __forceinline__ int SDOT4(int a, int b, int c) {
#pragma unroll
  for (int e = 0; e < 4; ++e)
    c += ((a << (24 - 8 * e)) >> 24) * ((b << (24 - 8 * e)) >> 24);
  return c;
}
#endif

// DPP (VALU pipe). Verified on this HW across R6-R9 first-run checks:
// 0x10N => lane i reads lane i+N; 0x11N row_shr chain + row_bcast; 0xB1 quad xor1.
#define DPP_ADD_F(var, ctrl, rmask)                                            \
  var += __builtin_bit_cast(float, __builtin_amdgcn_update_dpp(                \
      0, __builtin_bit_cast(int, var), (ctrl), (rmask), 0xf, true))
#define DPP_ADD_I(var, ctrl)                                                   \
  var += __builtin_amdgcn_update_dpp(0, (var), (ctrl), 0xf, 0xf, true)
#define DPP_MOV_I(dst, src, ctrl)                                              \
  dst = __builtin_amdgcn_update_dpp(0, (src), (ctrl), 0xf, 0xf, true)

__device__ __forceinline__ float wave_sum63(float p) {
  DPP_ADD_F(p, 0x111, 0xf);
  DPP_ADD_F(p, 0x112, 0xf);
  DPP_ADD_F(p, 0x114, 0xf);
  DPP_ADD_F(p, 0x118, 0xf);
  DPP_ADD_F(p, 0x142, 0xa);
  DPP_ADD_F(p, 0x143, 0xc);   // -> lane63 has wave total
  return p;
}

// ---- prep: per-row i8 quant of W_hh, packed for thread t=2d+half owning
// rows {d,256+d,512+d} x contiguous k-half [128*half, +128).
// wq[t*24 + g*8 + j] = 16 bytes k = 128*half + 16j .. +15 (LE within dwords).
__global__ void quant_whh(const float* __restrict__ W_hh, uint4* __restrict__ wq,
                          float* __restrict__ scales) {
  const int r = blockIdx.x * 256 + threadIdx.x;   // 0..767
  if (r >= 768) return;
  const float* row = W_hh + (size_t)r * HID;
  float amax = 0.0f;
  for (int k = 0; k < HID; ++k) amax = fmaxf(amax, fabsf(row[k]));
  amax = fmaxf(amax, 1e-20f);
  scales[r] = amax / 127.0f;
  const float inv = 127.0f / amax;
  const int g = r >> 8, d = r & 255;
  for (int half = 0; half < 2; ++half) {
    for (int j = 0; j < 8; ++j) {
      unsigned w[4];
#pragma unroll
      for (int u = 0; u < 4; ++u) {
        unsigned bb = 0;
#pragma unroll
        for (int e = 0; e < 4; ++e) {
          int qv = (int)rintf(row[128 * half + 16 * j + 4 * u + e] * inv);
          bb |= (unsigned)(qv & 0xff) << (8 * e);
        }
        w[u] = bb;
      }
      wq[(size_t)(2 * d + half) * 24 + g * 8 + j] = uint4{w[0], w[1], w[2], w[3]};
    }
  }
}

// One block per batch element, 512 threads (8 waves, 2/SIMD).
// R10 = R9's instruction diet, hardened + latency-reordered:
// - ALL barriers are real __syncthreads() (R9's hand-rolled lgkm-only barrier
//   is the prime suspect for its replay-timing-dependent divergence; the only
//   in-flight global at the barrier is the 1-step x prefetch, which has the
//   whole iteration to complete -> full barrier is ~free now).
// - Loop body reordered: the 96-sdot4 matvec burst issues FIRST; the hWb
//   (red) LDS read + 8-term sum + beta sigmoid chain come after, so their
//   ~150 cyc of latency overlap the dot burst instead of preceding it.
// - red slot rotation (write t&1, read (t-1)&1) kept; both slots zero-init.
__global__ __launch_bounds__(512, 1)
void momgru_persistent(const float* __restrict__ x,
                       const float* __restrict__ W_ih,
                       const float* __restrict__ b_ih,
                       const float* __restrict__ b_hh,
                       const float* __restrict__ Wb_x,
                       const float* __restrict__ Wb_h,
                       const float* __restrict__ b_beta,
                       const float* __restrict__ s_ptr,
                       const float* __restrict__ W_head,
                       const float* __restrict__ b_head,
                       const uint4* __restrict__ wq,
                       const float* __restrict__ scales,
                       float* __restrict__ out)  // [0,128) head, [128,128+B*T) betas
{
  const int b    = blockIdx.x;
  const int tid  = threadIdx.x;
  const int lane = tid & 63;
  const int wv   = tid >> 6;
  const int d    = tid >> 1;
  const int half = tid & 1;

  __shared__ unsigned hq[2][64];   // 512 B: h as i8, double-buffered
  __shared__ float    red[2][8];   // per-wave hWb partials (rotating slots)

  // ---- weights: 24 uint4 in registers (AGPR parking is benign, R7-proven) ----
  const uint4* wqt = wq + (size_t)tid * 24;
  uint4 wr[8], wz[8], wn[8];
#pragma unroll
  for (int j = 0; j < 8; ++j) wr[j] = wqt[j];
#pragma unroll
  for (int j = 0; j < 8; ++j) wz[j] = wqt[8 + j];
#pragma unroll
  for (int j = 0; j < 8; ++j) wn[j] = wqt[16 + j];

  // ---- per-thread constants (s pre-folded into input projection) ----
  const float sv = s_ptr[0];
  const half2_t wih_r = half2_t{(_Float16)(sv * W_ih[2 * d]),             (_Float16)(sv * W_ih[2 * d + 1])};
  const half2_t wih_z = half2_t{(_Float16)(sv * W_ih[2 * (HID + d)]),     (_Float16)(sv * W_ih[2 * (HID + d) + 1])};
  const half2_t wih_n = half2_t{(_Float16)(sv * W_ih[2 * (2 * HID + d)]), (_Float16)(sv * W_ih[2 * (2 * HID + d) + 1])};
  const float bih_r = sv * b_ih[d], bih_z = sv * b_ih[HID + d], bih_n = sv * b_ih[2 * HID + d];
  const float bhh_r = b_hh[d], bhh_z = b_hh[HID + d], bhh_n = b_hh[2 * HID + d];
  const float sc_r = scales[d] * (1.0f / 127.0f);
  const float sc_z = scales[HID + d] * (1.0f / 127.0f);
  const float sc_n = scales[2 * HID + d] * (1.0f / 127.0f);
  const half2_t wbx2 = half2_t{(_Float16)Wb_x[0], (_Float16)Wb_x[1]};  // uniform -> SGPR
  const float bbeta = b_beta[0];
  const float wbh_t = Wb_h[d];

  // ---- init ----
  if (tid < 128) reinterpret_cast<unsigned*>(hq)[tid] = 0u;
  if (tid < 16) reinterpret_cast<float*>(red)[tid] = 0.0f;   // both slots = 0
  float h_old = 0.0f, vr = 0.0f, vz = 0.0f, vn = 0.0f;
  float* betas = out + BATCH;
  const float2* xg2 = reinterpret_cast<const float2*>(x + (size_t)b * TLEN * 2);
  float2 xv = xg2[0];
  __syncthreads();

  int cur = 0;
  for (int t = 0; t < TLEN; ++t) {
    // ---- 1) matvec burst FIRST (depends only on hq[cur]) ----
    int ar = 0, az = 0, an = 0;
    const int4* hb = reinterpret_cast<const int4*>(hq[cur]);
#pragma unroll
    for (int j = 0; j < 8; ++j) {
      const int4 hv = hb[8 * half + j];
      ar = SDOT4(hv.x, wr[j].x, ar);
      az = SDOT4(hv.x, wz[j].x, az);
      an = SDOT4(hv.x, wn[j].x, an);
      ar = SDOT4(hv.y, wr[j].y, ar);
      az = SDOT4(hv.y, wz[j].y, az);
      an = SDOT4(hv.y, wn[j].y, an);
      ar = SDOT4(hv.z, wr[j].z, ar);
      az = SDOT4(hv.z, wz[j].z, az);
      an = SDOT4(hv.z, wn[j].z, an);
      ar = SDOT4(hv.w, wr[j].w, ar);
      az = SDOT4(hv.w, wz[j].w, az);
      an = SDOT4(hv.w, wn[j].w, an);
    }
    DPP_ADD_I(ar, 0xB1);
    DPP_ADD_I(az, 0xB1);
    DPP_ADD_I(an, 0xB1);

    // ---- 2) hWb (written at t-1, slot (t-1)&1) + beta + momentum ----
    const int rp = (t + 1) & 1;    // == (t-1)&1
    const float hWb = red[rp][0] + red[rp][1] + red[rp][2] + red[rp][3] +
                      red[rp][4] + red[rp][5] + red[rp][6] + red[rp][7];
    const half2_t x2 = half2_t{(_Float16)xv.x, (_Float16)xv.y};
    xv = xg2[(t + 1 < TLEN) ? t + 1 : t];
    const float beta = fast_sigmoid(dot2acc(x2, wbx2, hWb + bbeta));
    vr = beta * vr + dot2acc(x2, wih_r, bih_r);
    vz = beta * vz + dot2acc(x2, wih_z, bih_z);
    vn = beta * vn + dot2acc(x2, wih_n, bih_n);

    // ---- 3) gates ----
    const float r = fast_sigmoid(vr + (float)ar * sc_r + bhh_r);
    const float z = fast_sigmoid(vz + (float)az * sc_z + bhh_z);
    const float n = fast_tanh(vn + r * ((float)an * sc_n + bhh_n));
    h_old = (1.0f - z) * n + z * h_old;

    // ---- 4) quantize h -> i8; writer (tid&7)==0 packs dims d..d+3 ----
    const int nxt = cur ^ 1;
    const int qb = ((int)rintf(h_old * 127.0f)) & 0xff;
    int q2, q4, q6;
    DPP_MOV_I(q2, qb, 0x102);
    DPP_MOV_I(q4, qb, 0x104);
    DPP_MOV_I(q6, qb, 0x106);
    if ((tid & 7) == 0)
      hq[nxt][tid >> 3] = (unsigned)(qb | (q2 << 8) | (q4 << 16) | (q6 << 24));

    // ---- 5) next step's hWb partial -> red slot t&1 ----
    float p = (half == 0) ? h_old * wbh_t : 0.0f;
    p = wave_sum63(p);
    if (lane == 63) red[t & 1][wv] = p;
    if (tid == 63) betas[(size_t)b * TLEN + t] = beta;

    __syncthreads();
    cur = nxt;
  }

  // ---- head ----
  float hp = (half == 0) ? h_old * W_head[d] : 0.0f;
  hp = wave_sum63(hp);
  if (lane == 63) red[0][wv] = hp;
  __syncthreads();
  if (tid == 0) {
    out[b] = red[0][0] + red[0][1] + red[0][2] + red[0][3] +
             red[0][4] + red[0][5] + red[0][6] + red[0][7] + b_head[0];
  }
}

extern "C" void kernel_launch(void* const* d_in, const int* in_sizes, int n_in,
                              void* d_out, int out_size, void* d_ws, size_t ws_size,
                              hipStream_t stream) {
  const float* x      = (const float*)d_in[0];
  const float* W_ih   = (const float*)d_in[1];
  const float* W_hh   = (const float*)d_in[2];
  const float* b_ih   = (const float*)d_in[3];
  const float* b_hh   = (const float*)d_in[4];
  const float* Wb_x   = (const float*)d_in[5];
  const float* Wb_h   = (const float*)d_in[6];
  const float* b_beta = (const float*)d_in[7];
  const float* s      = (const float*)d_in[8];
  const float* W_head = (const float*)d_in[9];
  const float* b_head = (const float*)d_in[10];
  float* out = (float*)d_out;

  uint4* wq     = (uint4*)d_ws;                              // 512*24*16 = 192 KB
  float* scales = (float*)((char*)d_ws + 512 * 24 * 16);     // +3 KB

  quant_whh<<<dim3(3), dim3(256), 0, stream>>>(W_hh, wq, scales);
  momgru_persistent<<<dim3(BATCH), dim3(512), 0, stream>>>(
      x, W_ih, b_ih, b_hh, Wb_x, Wb_h, b_beta, s, W_head, b_head,
      (const uint4*)wq, (const float*)scales, out);
}

// Round 11
// 891.043 us; speedup vs baseline: 1.2306x; 1.0784x over previous
//
#include <hip/hip_runtime.h>

#define HID 256
#define TLEN 1024
#define BATCH 128

typedef _Float16 half2_t __attribute__((ext_vector_type(2)));

__device__ __forceinline__ float fexp2(float x) { return __builtin_amdgcn_exp2f(x); }
__device__ __forceinline__ float frcp(float x)  { return __builtin_amdgcn_rcpf(x); }
__device__ __forceinline__ float fast_sigmoid(float x) {
  return frcp(1.0f + fexp2(-1.442695040888963f * x));
}
__device__ __forceinline__ float fast_tanh(float x) {
  float e = fexp2(2.885390081777927f * x);
  return 1.0f - 2.0f * frcp(e + 1.0f);
}
__device__ __forceinline__ float dot2acc(half2_t a, half2_t b, float c) {
  return __builtin_amdgcn_fdot2(a, b, c, false);   // v_dot2_f32_f16
}

#if defined(__has_builtin) && __has_builtin(__builtin_amdgcn_sdot4)
#define SDOT4(a, b, c) __builtin_amdgcn_sdot4((int)(a), (int)(b), (c), false)
#else
__device__ __forceinline__ int SDOT4(int a, int b, int c) {
#pragma unroll
  for (int e = 0; e < 4; ++e)
    c += ((a << (24 - 8 * e)) >> 24) * ((b << (24 - 8 * e)) >> 24);
  return c;
}
#endif

// DPP (VALU pipe). Verified on this HW R6-R10: 0x10N => lane i reads lane i+N
// (within 16-lane row); 0x11N row_shr chain + 0x142/0x143 row_bcast; all
// first-run correctness checks passed with these.
#define DPP_ADD_F(var, ctrl, rmask)                                            \
  var += __builtin_bit_cast(float, __builtin_amdgcn_update_dpp(                \
      0, __builtin_bit_cast(int, var), (ctrl), (rmask), 0xf, true))
#define DPP_MOV_I(dst, src, ctrl)                                              \
  dst = __builtin_amdgcn_update_dpp(0, (src), (ctrl), 0xf, 0xf, true)

__device__ __forceinline__ float wave_sum63(float p) {
  DPP_ADD_F(p, 0x111, 0xf);
  DPP_ADD_F(p, 0x112, 0xf);
  DPP_ADD_F(p, 0x114, 0xf);
  DPP_ADD_F(p, 0x118, 0xf);
  DPP_ADD_F(p, 0x142, 0xa);
  DPP_ADD_F(p, 0x143, 0xc);   // -> lane63 has wave total
  return p;
}

// ---- prep: per-row i8 quant of W_hh (768x256). New layout for R11's
// one-thread-per-dim mapping: thread t owns rows {t, 256+t, 512+t} full-k.
// wq[t*48 + g*16 + c] = 16 bytes of row (g*256+t), k in [16c, 16c+16).
__global__ void quant_whh(const float* __restrict__ W_hh, uint4* __restrict__ wq,
                          float* __restrict__ scales) {
  const int r = blockIdx.x * 256 + threadIdx.x;   // 0..767
  if (r >= 768) return;
  const float* row = W_hh + (size_t)r * HID;
  float amax = 0.0f;
  for (int k = 0; k < HID; ++k) amax = fmaxf(amax, fabsf(row[k]));
  amax = fmaxf(amax, 1e-20f);
  scales[r] = amax / 127.0f;
  const float inv = 127.0f / amax;
  const int g = r >> 8, dd = r & 255;
  for (int c = 0; c < 16; ++c) {
    unsigned w[4];
#pragma unroll
    for (int u = 0; u < 4; ++u) {
      unsigned bb = 0;
#pragma unroll
      for (int e = 0; e < 4; ++e) {
        int qv = (int)rintf(row[16 * c + 4 * u + e] * inv);
        bb |= (unsigned)(qv & 0xff) << (8 * e);
      }
      w[u] = bb;
    }
    wq[(size_t)dd * 48 + g * 16 + c] = uint4{w[0], w[1], w[2], w[3]};
  }
}

// One block per batch element, 256 threads (4 waves, 1 wave/SIMD).
// R11: thread d owns dim d COMPLETELY (rows d, 256+d, 512+d; full k) = 48
// uint4 = 192 weight dwords. Demand ~238 arch VGPRs <= the 256 arch max the
// allocator fills under launch_bounds(256,1) (R1-proven) -> no AGPR parking
// (R10's VGPR_Count=68 showed ~96 parked dwords costing ~2x readback instr),
// and per-dim gate/momentum/reduce work is no longer duplicated across 2
// waves. Total sdot4 cycles per SIMD unchanged; everything else halves.
__global__ __launch_bounds__(256, 1)
void momgru_persistent(const float* __restrict__ x,
                       const float* __restrict__ W_ih,
                       const float* __restrict__ b_ih,
                       const float* __restrict__ b_hh,
                       const float* __restrict__ Wb_x,
                       const float* __restrict__ Wb_h,
                       const float* __restrict__ b_beta,
                       const float* __restrict__ s_ptr,
                       const float* __restrict__ W_head,
                       const float* __restrict__ b_head,
                       const uint4* __restrict__ wq,
                       const float* __restrict__ scales,
                       float* __restrict__ out)  // [0,128) head, [128,128+B*T) betas
{
  const int b    = blockIdx.x;
  const int tid  = threadIdx.x;   // == dim d
  const int lane = tid & 63;
  const int wv   = tid >> 6;      // 0..3

  __shared__ unsigned hq[2][64];  // 512 B: h as i8, double-buffered
  __shared__ float    red[2][4];  // per-wave hWb partials (rotating slots)

  // ---- weights: 48 uint4 in arch registers ----
  const uint4* wqt = wq + (size_t)tid * 48;
  uint4 wr[16], wz[16], wn[16];
#pragma unroll
  for (int j = 0; j < 16; ++j) wr[j] = wqt[j];
#pragma unroll
  for (int j = 0; j < 16; ++j) wz[j] = wqt[16 + j];
#pragma unroll
  for (int j = 0; j < 16; ++j) wn[j] = wqt[32 + j];

  // ---- per-thread constants (s pre-folded into input projection) ----
  const float sv = s_ptr[0];
  const half2_t wih_r = half2_t{(_Float16)(sv * W_ih[2 * tid]),             (_Float16)(sv * W_ih[2 * tid + 1])};
  const half2_t wih_z = half2_t{(_Float16)(sv * W_ih[2 * (HID + tid)]),     (_Float16)(sv * W_ih[2 * (HID + tid) + 1])};
  const half2_t wih_n = half2_t{(_Float16)(sv * W_ih[2 * (2 * HID + tid)]), (_Float16)(sv * W_ih[2 * (2 * HID + tid) + 1])};
  const float bih_r = sv * b_ih[tid], bih_z = sv * b_ih[HID + tid], bih_n = sv * b_ih[2 * HID + tid];
  const float bhh_r = b_hh[tid], bhh_z = b_hh[HID + tid], bhh_n = b_hh[2 * HID + tid];
  const float sc_r = scales[tid] * (1.0f / 127.0f);
  const float sc_z = scales[HID + tid] * (1.0f / 127.0f);
  const float sc_n = scales[2 * HID + tid] * (1.0f / 127.0f);
  const half2_t wbx2 = half2_t{(_Float16)Wb_x[0], (_Float16)Wb_x[1]};  // uniform -> SGPR
  const float bbeta = b_beta[0];
  const float wbh_t = Wb_h[tid];

  // ---- init ----
  if (tid < 128) reinterpret_cast<unsigned*>(hq)[tid] = 0u;
  if (tid < 8) reinterpret_cast<float*>(red)[tid] = 0.0f;   // both slots = 0
  float h_old = 0.0f, vr = 0.0f, vz = 0.0f, vn = 0.0f;
  float* betas = out + BATCH;
  const float2* xg2 = reinterpret_cast<const float2*>(x + (size_t)b * TLEN * 2);
  float2 xv = xg2[0];
  __syncthreads();

  int cur = 0;
  for (int t = 0; t < TLEN; ++t) {
    // ---- 1) full-k i8 matvec burst (depends only on hq[cur]) ----
    int ar = 0, az = 0, an = 0;
    const int4* hb = reinterpret_cast<const int4*>(hq[cur]);   // 16 x int4
#pragma unroll
    for (int c = 0; c < 16; ++c) {
      const int4 hv = hb[c];
      ar = SDOT4(hv.x, wr[c].x, ar);
      az = SDOT4(hv.x, wz[c].x, az);
      an = SDOT4(hv.x, wn[c].x, an);
      ar = SDOT4(hv.y, wr[c].y, ar);
      az = SDOT4(hv.y, wz[c].y, az);
      an = SDOT4(hv.y, wn[c].y, an);
      ar = SDOT4(hv.z, wr[c].z, ar);
      az = SDOT4(hv.z, wz[c].z, az);
      an = SDOT4(hv.z, wn[c].z, an);
      ar = SDOT4(hv.w, wr[c].w, ar);
      az = SDOT4(hv.w, wz[c].w, az);
      an = SDOT4(hv.w, wn[c].w, an);
    }

    // ---- 2) hWb (written at t-1, slot (t-1)&1) + beta + momentum ----
    const int rp = (t + 1) & 1;
    const float hWb = red[rp][0] + red[rp][1] + red[rp][2] + red[rp][3];
    const half2_t x2 = half2_t{(_Float16)xv.x, (_Float16)xv.y};
    xv = xg2[(t + 1 < TLEN) ? t + 1 : t];
    const float beta = fast_sigmoid(dot2acc(x2, wbx2, hWb + bbeta));
    vr = beta * vr + dot2acc(x2, wih_r, bih_r);
    vz = beta * vz + dot2acc(x2, wih_z, bih_z);
    vn = beta * vn + dot2acc(x2, wih_n, bih_n);

    // ---- 3) gates ----
    const float r = fast_sigmoid(vr + (float)ar * sc_r + bhh_r);
    const float z = fast_sigmoid(vz + (float)az * sc_z + bhh_z);
    const float n = fast_tanh(vn + r * ((float)an * sc_n + bhh_n));
    h_old = (1.0f - z) * n + z * h_old;

    // ---- 4) quantize h -> i8; writer (tid&3)==0 packs dims d..d+3 ----
    const int nxt = cur ^ 1;
    const int qb = ((int)rintf(h_old * 127.0f)) & 0xff;
    int q1, q2, q3;
    DPP_MOV_I(q1, qb, 0x101);
    DPP_MOV_I(q2, qb, 0x102);
    DPP_MOV_I(q3, qb, 0x103);
    if ((tid & 3) == 0)
      hq[nxt][tid >> 2] = (unsigned)(qb | (q1 << 8) | (q2 << 16) | (q3 << 24));

    // ---- 5) next step's hWb partial -> red slot t&1 (every lane = 1 dim) ----
    float p = h_old * wbh_t;
    p = wave_sum63(p);
    if (lane == 63) red[t & 1][wv] = p;
    if (tid == 0) betas[(size_t)b * TLEN + t] = beta;

    __syncthreads();
    cur = nxt;
  }

  // ---- head ----
  float hp = h_old * W_head[tid];
  hp = wave_sum63(hp);
  if (lane == 63) red[0][wv] = hp;
  __syncthreads();
  if (tid == 0) out[b] = red[0][0] + red[0][1] + red[0][2] + red[0][3] + b_head[0];
}

extern "C" void kernel_launch(void* const* d_in, const int* in_sizes, int n_in,
                              void* d_out, int out_size, void* d_ws, size_t ws_size,
                              hipStream_t stream) {
  const float* x      = (const float*)d_in[0];
  const float* W_ih   = (const float*)d_in[1];
  const float* W_hh   = (const float*)d_in[2];
  const float* b_ih   = (const float*)d_in[3];
  const float* b_hh   = (const float*)d_in[4];
  const float* Wb_x   = (const float*)d_in[5];
  const float* Wb_h   = (const float*)d_in[6];
  const float* b_beta = (const float*)d_in[7];
  const float* s      = (const float*)d_in[8];
  const float* W_head = (const float*)d_in[9];
  const float* b_head = (const float*)d_in[10];
  float* out = (float*)d_out;

  uint4* wq     = (uint4*)d_ws;                              // 256*48*16 = 192 KB
  float* scales = (float*)((char*)d_ws + 256 * 48 * 16);     // +3 KB

  quant_whh<<<dim3(3), dim3(256), 0, stream>>>(W_hh, wq, scales);
  momgru_persistent<<<dim3(BATCH), dim3(256), 0, stream>>>(
      x, W_ih, b_ih, b_hh, Wb_x, Wb_h, b_beta, s, W_head, b_head,
      (const uint4*)wq, (const float*)scales, out);
}

// Round 12
// 846.971 us; speedup vs baseline: 1.2946x; 1.0520x over previous
//
#include <hip/hip_runtime.h>

#define HID 256
#define TLEN 1024
#define BATCH 128

typedef _Float16 half2_t __attribute__((ext_vector_type(2)));

__device__ __forceinline__ float fexp2(float x) { return __builtin_amdgcn_exp2f(x); }
__device__ __forceinline__ float frcp(float x)  { return __builtin_amdgcn_rcpf(x); }
__device__ __forceinline__ float fast_sigmoid(float x) {
  return frcp(1.0f + fexp2(-1.442695040888963f * x));
}
__device__ __forceinline__ float fast_tanh(float x) {
  float e = fexp2(2.885390081777927f * x);
  return 1.0f - 2.0f * frcp(e + 1.0f);
}
__device__ __forceinline__ float dot2acc(half2_t a, half2_t b, float c) {
  return __builtin_amdgcn_fdot2(a, b, c, false);   // v_dot2_f32_f16
}

#if defined(__has_builtin) && __has_builtin(__builtin_amdgcn_sdot4)
#define SDOT4(a, b, c) __builtin_amdgcn_sdot4((int)(a), (int)(b), (c), false)
#else
__device__ __forceinline__ int SDOT4(int a, int b, int c) {
#pragma unroll
  for (int e = 0; e < 4; ++e)
    c += ((a << (24 - 8 * e)) >> 24) * ((b << (24 - 8 * e)) >> 24);
  return c;
}
#endif

// DPP (VALU pipe). Verified on this HW R6-R11.
#define DPP_ADD_F(var, ctrl, rmask)                                            \
  var += __builtin_bit_cast(float, __builtin_amdgcn_update_dpp(                \
      0, __builtin_bit_cast(int, var), (ctrl), (rmask), 0xf, true))

__device__ __forceinline__ float wave_sum63(float p) {
  DPP_ADD_F(p, 0x111, 0xf);
  DPP_ADD_F(p, 0x112, 0xf);
  DPP_ADD_F(p, 0x114, 0xf);
  DPP_ADD_F(p, 0x118, 0xf);
  DPP_ADD_F(p, 0x142, 0xa);
  DPP_ADD_F(p, 0x143, 0xc);   // -> lane63 has wave total
  return p;
}

// ---- prep: per-row i8 quant of W_hh (768x256) for one-thread-per-dim:
// wq[t*48 + g*16 + c] = 16 bytes of row (g*256+t), k in [16c, 16c+16).
__global__ void quant_whh(const float* __restrict__ W_hh, uint4* __restrict__ wq,
                          float* __restrict__ scales) {
  const int r = blockIdx.x * 256 + threadIdx.x;   // 0..767
  if (r >= 768) return;
  const float* row = W_hh + (size_t)r * HID;
  float amax = 0.0f;
  for (int k = 0; k < HID; ++k) amax = fmaxf(amax, fabsf(row[k]));
  amax = fmaxf(amax, 1e-20f);
  scales[r] = amax / 127.0f;
  const float inv = 127.0f / amax;
  const int g = r >> 8, dd = r & 255;
  for (int c = 0; c < 16; ++c) {
    unsigned w[4];
#pragma unroll
    for (int u = 0; u < 4; ++u) {
      unsigned bb = 0;
#pragma unroll
      for (int e = 0; e < 4; ++e) {
        int qv = (int)rintf(row[16 * c + 4 * u + e] * inv);
        bb |= (unsigned)(qv & 0xff) << (8 * e);
      }
      w[u] = bb;
    }
    wq[(size_t)dd * 48 + g * 16 + c] = uint4{w[0], w[1], w[2], w[3]};
  }
}

// One block per batch element, 256 threads (4 waves, 1 wave/SIMD).
// R12 = R11 + two changes:
// (1) amdgpu_waves_per_eu(1,1): the R11 counters showed the allocator still
//     budgets for 2 co-resident blocks (120 arch VGPR + ~130 AGPR-parked,
//     250x256x2 = exactly the 512KB file). max=1 wave/EU makes 1-block/CU
//     the declared occupancy -> full unified budget per wave -> the 250-dword
//     demand fits in arch VGPRs, no per-step v_accvgpr_read tax.
// (2) h write as ds_write_b8 per thread (1 instr) instead of DPP-pack + b32.
__global__
__attribute__((amdgpu_flat_work_group_size(256, 256)))
__attribute__((amdgpu_waves_per_eu(1, 1)))
void momgru_persistent(const float* __restrict__ x,
                       const float* __restrict__ W_ih,
                       const float* __restrict__ b_ih,
                       const float* __restrict__ b_hh,
                       const float* __restrict__ Wb_x,
                       const float* __restrict__ Wb_h,
                       const float* __restrict__ b_beta,
                       const float* __restrict__ s_ptr,
                       const float* __restrict__ W_head,
                       const float* __restrict__ b_head,
                       const uint4* __restrict__ wq,
                       const float* __restrict__ scales,
                       float* __restrict__ out)  // [0,128) head, [128,128+B*T) betas
{
  const int b    = blockIdx.x;
  const int tid  = threadIdx.x;   // == dim d
  const int lane = tid & 63;
  const int wv   = tid >> 6;      // 0..3

  __shared__ unsigned hq[2][64];  // 512 B: h as i8, double-buffered
  __shared__ float    red[2][4];  // per-wave hWb partials (rotating slots)

  // ---- weights: 48 uint4 in arch registers ----
  const uint4* wqt = wq + (size_t)tid * 48;
  uint4 wr[16], wz[16], wn[16];
#pragma unroll
  for (int j = 0; j < 16; ++j) wr[j] = wqt[j];
#pragma unroll
  for (int j = 0; j < 16; ++j) wz[j] = wqt[16 + j];
#pragma unroll
  for (int j = 0; j < 16; ++j) wn[j] = wqt[32 + j];

  // ---- per-thread constants (s pre-folded into input projection) ----
  const float sv = s_ptr[0];
  const half2_t wih_r = half2_t{(_Float16)(sv * W_ih[2 * tid]),             (_Float16)(sv * W_ih[2 * tid + 1])};
  const half2_t wih_z = half2_t{(_Float16)(sv * W_ih[2 * (HID + tid)]),     (_Float16)(sv * W_ih[2 * (HID + tid) + 1])};
  const half2_t wih_n = half2_t{(_Float16)(sv * W_ih[2 * (2 * HID + tid)]), (_Float16)(sv * W_ih[2 * (2 * HID + tid) + 1])};
  const float bih_r = sv * b_ih[tid], bih_z = sv * b_ih[HID + tid], bih_n = sv * b_ih[2 * HID + tid];
  const float bhh_r = b_hh[tid], bhh_z = b_hh[HID + tid], bhh_n = b_hh[2 * HID + tid];
  const float sc_r = scales[tid] * (1.0f / 127.0f);
  const float sc_z = scales[HID + tid] * (1.0f / 127.0f);
  const float sc_n = scales[2 * HID + tid] * (1.0f / 127.0f);
  const half2_t wbx2 = half2_t{(_Float16)Wb_x[0], (_Float16)Wb_x[1]};  // uniform -> SGPR
  const float bbeta = b_beta[0];
  const float wbh_t = Wb_h[tid];

  // ---- init ----
  if (tid < 128) reinterpret_cast<unsigned*>(hq)[tid] = 0u;
  if (tid < 8) reinterpret_cast<float*>(red)[tid] = 0.0f;   // both slots = 0
  float h_old = 0.0f, vr = 0.0f, vz = 0.0f, vn = 0.0f;
  float* betas = out + BATCH;
  const float2* xg2 = reinterpret_cast<const float2*>(x + (size_t)b * TLEN * 2);
  float2 xv = xg2[0];
  __syncthreads();

  int cur = 0;
  for (int t = 0; t < TLEN; ++t) {
    // ---- 1) full-k i8 matvec burst (depends only on hq[cur]) ----
    int ar = 0, az = 0, an = 0;
    const int4* hb = reinterpret_cast<const int4*>(hq[cur]);   // 16 x int4
#pragma unroll
    for (int c = 0; c < 16; ++c) {
      const int4 hv = hb[c];
      ar = SDOT4(hv.x, wr[c].x, ar);
      az = SDOT4(hv.x, wz[c].x, az);
      an = SDOT4(hv.x, wn[c].x, an);
      ar = SDOT4(hv.y, wr[c].y, ar);
      az = SDOT4(hv.y, wz[c].y, az);
      an = SDOT4(hv.y, wn[c].y, an);
      ar = SDOT4(hv.z, wr[c].z, ar);
      az = SDOT4(hv.z, wz[c].z, az);
      an = SDOT4(hv.z, wn[c].z, an);
      ar = SDOT4(hv.w, wr[c].w, ar);
      az = SDOT4(hv.w, wz[c].w, az);
      an = SDOT4(hv.w, wn[c].w, an);
    }

    // ---- 2) hWb (written at t-1, slot (t-1)&1) + beta + momentum ----
    const int rp = (t + 1) & 1;
    const float hWb = red[rp][0] + red[rp][1] + red[rp][2] + red[rp][3];
    const half2_t x2 = half2_t{(_Float16)xv.x, (_Float16)xv.y};
    xv = xg2[(t + 1 < TLEN) ? t + 1 : t];
    const float beta = fast_sigmoid(dot2acc(x2, wbx2, hWb + bbeta));
    vr = beta * vr + dot2acc(x2, wih_r, bih_r);
    vz = beta * vz + dot2acc(x2, wih_z, bih_z);
    vn = beta * vn + dot2acc(x2, wih_n, bih_n);

    // ---- 3) gates ----
    const float r = fast_sigmoid(vr + (float)ar * sc_r + bhh_r);
    const float z = fast_sigmoid(vz + (float)az * sc_z + bhh_z);
    const float n = fast_tanh(vn + r * ((float)an * sc_n + bhh_n));
    h_old = (1.0f - z) * n + z * h_old;

    // ---- 4) quantize h -> i8, one byte store per thread ----
    const int nxt = cur ^ 1;
    const int qb = (int)rintf(h_old * 127.0f);
    reinterpret_cast<unsigned char*>(hq[nxt])[tid] = (unsigned char)(qb & 0xff);

    // ---- 5) next step's hWb partial -> red slot t&1 (every lane = 1 dim) ----
    float p = h_old * wbh_t;
    p = wave_sum63(p);
    if (lane == 63) red[t & 1][wv] = p;
    if (tid == 0) betas[(size_t)b * TLEN + t] = beta;

    __syncthreads();
    cur = nxt;
  }

  // ---- head ----
  float hp = h_old * W_head[tid];
  hp = wave_sum63(hp);
  if (lane == 63) red[0][wv] = hp;
  __syncthreads();
  if (tid == 0) out[b] = red[0][0] + red[0][1] + red[0][2] + red[0][3] + b_head[0];
}

extern "C" void kernel_launch(void* const* d_in, const int* in_sizes, int n_in,
                              void* d_out, int out_size, void* d_ws, size_t ws_size,
                              hipStream_t stream) {
  const float* x      = (const float*)d_in[0];
  const float* W_ih   = (const float*)d_in[1];
  const float* W_hh   = (const float*)d_in[2];
  const float* b_ih   = (const float*)d_in[3];
  const float* b_hh   = (const float*)d_in[4];
  const float* Wb_x   = (const float*)d_in[5];
  const float* Wb_h   = (const float*)d_in[6];
  const float* b_beta = (const float*)d_in[7];
  const float* s      = (const float*)d_in[8];
  const float* W_head = (const float*)d_in[9];
  const float* b_head = (const float*)d_in[10];
  float* out = (float*)d_out;

  uint4* wq     = (uint4*)d_ws;                              // 256*48*16 = 192 KB
  float* scales = (float*)((char*)d_ws + 256 * 48 * 16);     // +3 KB

  quant_whh<<<dim3(3), dim3(256), 0, stream>>>(W_hh, wq, scales);
  momgru_persistent<<<dim3(BATCH), dim3(256), 0, stream>>>(
      x, W_ih, b_ih, b_hh, Wb_x, Wb_h, b_beta, s, W_head, b_head,
      (const uint4*)wq, (const float*)scales, out);
}

// Round 13
// 824.948 us; speedup vs baseline: 1.3292x; 1.0267x over previous
//
#include <hip/hip_runtime.h>

#define HID 256
#define TLEN 1024
#define BATCH 128

typedef _Float16 half2_t __attribute__((ext_vector_type(2)));

__device__ __forceinline__ float fexp2(float x) { return __builtin_amdgcn_exp2f(x); }
__device__ __forceinline__ float frcp(float x)  { return __builtin_amdgcn_rcpf(x); }
__device__ __forceinline__ float fast_sigmoid(float x) {
  return frcp(1.0f + fexp2(-1.442695040888963f * x));
}
__device__ __forceinline__ float fast_tanh(float x) {
  float e = fexp2(2.885390081777927f * x);
  return 1.0f - 2.0f * frcp(e + 1.0f);
}
__device__ __forceinline__ float dot2acc(half2_t a, half2_t b, float c) {
  return __builtin_amdgcn_fdot2(a, b, c, false);   // v_dot2_f32_f16
}

#if defined(__has_builtin) && __has_builtin(__builtin_amdgcn_sdot4)
#define SDOT4(a, b, c) __builtin_amdgcn_sdot4((int)(a), (int)(b), (c), false)
#else
__device__ __forceinline__ int SDOT4(int a, int b, int c) {
#pragma unroll
  for (int e = 0; e < 4; ++e)
    c += ((a << (24 - 8 * e)) >> 24) * ((b << (24 - 8 * e)) >> 24);
  return c;
}
#endif

// DPP (VALU pipe). Verified on this HW R6-R12.
#define DPP_ADD_F(var, ctrl, rmask)                                            \
  var += __builtin_bit_cast(float, __builtin_amdgcn_update_dpp(                \
      0, __builtin_bit_cast(int, var), (ctrl), (rmask), 0xf, true))
#define DPP_ADD_I(var, ctrl, rmask)                                            \
  var += __builtin_amdgcn_update_dpp(0, (var), (ctrl), (rmask), 0xf, true)

__device__ __forceinline__ float wave_sum63_f(float p) {
  DPP_ADD_F(p, 0x111, 0xf);
  DPP_ADD_F(p, 0x112, 0xf);
  DPP_ADD_F(p, 0x114, 0xf);
  DPP_ADD_F(p, 0x118, 0xf);
  DPP_ADD_F(p, 0x142, 0xa);
  DPP_ADD_F(p, 0x143, 0xc);   // -> lane63 has wave total
  return p;
}
__device__ __forceinline__ int wave_sum63_i(int p) {
  DPP_ADD_I(p, 0x111, 0xf);
  DPP_ADD_I(p, 0x112, 0xf);
  DPP_ADD_I(p, 0x114, 0xf);
  DPP_ADD_I(p, 0x118, 0xf);
  DPP_ADD_I(p, 0x142, 0xa);
  DPP_ADD_I(p, 0x143, 0xc);   // -> lane63 has wave total (exact, int)
  return p;
}

// ---- prep: per-row i8 quant of W_hh (768x256) for one-thread-per-dim
// (wq[t*48 + g*16 + c]); plus i8 pack of Wb_h (word i = dims 4i..4i+3) with
// folded scale (amax/127 * 1/127) so hWb = sdot_total * wbscale.
__global__ void quant_whh(const float* __restrict__ W_hh,
                          const float* __restrict__ Wb_h,
                          uint4* __restrict__ wq,
                          float* __restrict__ scales,
                          unsigned* __restrict__ wbq,
                          float* __restrict__ wbscale) {
  const int r = blockIdx.x * 256 + threadIdx.x;   // 0..1023
  if (r < 768) {
    const float* row = W_hh + (size_t)r * HID;
    float amax = 0.0f;
    for (int k = 0; k < HID; ++k) amax = fmaxf(amax, fabsf(row[k]));
    amax = fmaxf(amax, 1e-20f);
    scales[r] = amax / 127.0f;
    const float inv = 127.0f / amax;
    const int g = r >> 8, dd = r & 255;
    for (int c = 0; c < 16; ++c) {
      unsigned w[4];
#pragma unroll
      for (int u = 0; u < 4; ++u) {
        unsigned bb = 0;
#pragma unroll
        for (int e = 0; e < 4; ++e) {
          int qv = (int)rintf(row[16 * c + 4 * u + e] * inv);
          bb |= (unsigned)(qv & 0xff) << (8 * e);
        }
        w[u] = bb;
      }
      wq[(size_t)dd * 48 + g * 16 + c] = uint4{w[0], w[1], w[2], w[3]};
    }
  } else if (r < 832) {
    // threads 768..831: pack Wb_h word (r-768); amax computed redundantly
    float amax = 0.0f;
    for (int k = 0; k < HID; ++k) amax = fmaxf(amax, fabsf(Wb_h[k]));
    amax = fmaxf(amax, 1e-20f);
    const float inv = 127.0f / amax;
    const int i = r - 768;
    unsigned bb = 0;
#pragma unroll
    for (int e = 0; e < 4; ++e) {
      int qv = (int)rintf(Wb_h[4 * i + e] * inv);
      bb |= (unsigned)(qv & 0xff) << (8 * e);
    }
    wbq[i] = bb;
    if (i == 0) wbscale[0] = (amax / 127.0f) * (1.0f / 127.0f);
  }
}

// One block per batch element, 256 threads (4 waves, 1 wave/SIMD).
// R13 = R12 + (a) hWb computed per-wave from the i8 h words (1 ds_read_b32 +
// 1 sdot4 vs Wb_h-i8 + int DPP wave-sum + readlane) -- removes the red[] LDS
// round-trip from the per-step critical path; (b) 6 sdot accumulators (2 per
// gate) to cover sdot4 dep latency. AGPR parking of ~120 weight dwords is
// accepted: 3 attribute attempts pinned the arch grant at ~128, and parking
// reads (512 B/cyc/CU) beat any LDS fallback (128 B/cyc/CU).
__global__
__attribute__((amdgpu_flat_work_group_size(256, 256)))
__attribute__((amdgpu_waves_per_eu(1, 1)))
void momgru_persistent(const float* __restrict__ x,
                       const float* __restrict__ W_ih,
                       const float* __restrict__ b_ih,
                       const float* __restrict__ b_hh,
                       const float* __restrict__ Wb_x,
                       const float* __restrict__ b_beta,
                       const float* __restrict__ s_ptr,
                       const float* __restrict__ W_head,
                       const float* __restrict__ b_head,
                       const uint4* __restrict__ wq,
                       const float* __restrict__ scales,
                       const unsigned* __restrict__ wbq,
                       const float* __restrict__ wbscale,
                       float* __restrict__ out)  // [0,128) head, [128,128+B*T) betas
{
  const int b    = blockIdx.x;
  const int tid  = threadIdx.x;   // == dim d
  const int lane = tid & 63;
  const int wv   = tid >> 6;      // 0..3

  __shared__ unsigned hq[2][64];  // 512 B: h as i8, double-buffered
  __shared__ float    red[4];     // head reduce only

  // ---- weights: 48 uint4 (arch regs + AGPR-parked overflow) ----
  const uint4* wqt = wq + (size_t)tid * 48;
  uint4 wr[16], wz[16], wn[16];
#pragma unroll
  for (int j = 0; j < 16; ++j) wr[j] = wqt[j];
#pragma unroll
  for (int j = 0; j < 16; ++j) wz[j] = wqt[16 + j];
#pragma unroll
  for (int j = 0; j < 16; ++j) wn[j] = wqt[32 + j];

  // ---- per-thread constants (s pre-folded into input projection) ----
  const float sv = s_ptr[0];
  const half2_t wih_r = half2_t{(_Float16)(sv * W_ih[2 * tid]),             (_Float16)(sv * W_ih[2 * tid + 1])};
  const half2_t wih_z = half2_t{(_Float16)(sv * W_ih[2 * (HID + tid)]),     (_Float16)(sv * W_ih[2 * (HID + tid) + 1])};
  const half2_t wih_n = half2_t{(_Float16)(sv * W_ih[2 * (2 * HID + tid)]), (_Float16)(sv * W_ih[2 * (2 * HID + tid) + 1])};
  const float bih_r = sv * b_ih[tid], bih_z = sv * b_ih[HID + tid], bih_n = sv * b_ih[2 * HID + tid];
  const float bhh_r = b_hh[tid], bhh_z = b_hh[HID + tid], bhh_n = b_hh[2 * HID + tid];
  const float sc_r = scales[tid] * (1.0f / 127.0f);
  const float sc_z = scales[HID + tid] * (1.0f / 127.0f);
  const float sc_n = scales[2 * HID + tid] * (1.0f / 127.0f);
  const half2_t wbx2 = half2_t{(_Float16)Wb_x[0], (_Float16)Wb_x[1]};  // uniform -> SGPR
  const float bbeta = b_beta[0];
  const unsigned wbq_l = wbq[lane];       // Wb_h i8, dims 4*lane..4*lane+3
  const float wbsc = wbscale[0];          // folded (amax/127)*(1/127)

  // ---- init ----
  if (tid < 128) reinterpret_cast<unsigned*>(hq)[tid] = 0u;
  if (tid < 4) red[tid] = 0.0f;
  float h_old = 0.0f, vr = 0.0f, vz = 0.0f, vn = 0.0f;
  float* betas = out + BATCH;
  const float2* xg2 = reinterpret_cast<const float2*>(x + (size_t)b * TLEN * 2);
  float2 xv = xg2[0];
  __syncthreads();

  int cur = 0;
  for (int t = 0; t < TLEN; ++t) {
    // ---- A) per-wave hWb from h_{t-1} i8 words (no LDS round-trip) ----
    const unsigned hw_l = reinterpret_cast<const unsigned*>(hq[cur])[lane];
    int hwb_i = SDOT4(hw_l, wbq_l, 0);
    hwb_i = wave_sum63_i(hwb_i);

    // ---- B) full-k i8 matvec burst, 6 accumulators ----
    int ar0 = 0, az0 = 0, an0 = 0, ar1 = 0, az1 = 0, an1 = 0;
    const int4* hb = reinterpret_cast<const int4*>(hq[cur]);   // 16 x int4
#pragma unroll
    for (int c = 0; c < 8; ++c) {
      const int4 h0 = hb[2 * c];
      const int4 h1 = hb[2 * c + 1];
      ar0 = SDOT4(h0.x, wr[2 * c].x, ar0);
      az0 = SDOT4(h0.x, wz[2 * c].x, az0);
      an0 = SDOT4(h0.x, wn[2 * c].x, an0);
      ar1 = SDOT4(h1.x, wr[2 * c + 1].x, ar1);
      az1 = SDOT4(h1.x, wz[2 * c + 1].x, az1);
      an1 = SDOT4(h1.x, wn[2 * c + 1].x, an1);
      ar0 = SDOT4(h0.y, wr[2 * c].y, ar0);
      az0 = SDOT4(h0.y, wz[2 * c].y, az0);
      an0 = SDOT4(h0.y, wn[2 * c].y, an0);
      ar1 = SDOT4(h1.y, wr[2 * c + 1].y, ar1);
      az1 = SDOT4(h1.y, wz[2 * c + 1].y, az1);
      an1 = SDOT4(h1.y, wn[2 * c + 1].y, an1);
      ar0 = SDOT4(h0.z, wr[2 * c].z, ar0);
      az0 = SDOT4(h0.z, wz[2 * c].z, az0);
      an0 = SDOT4(h0.z, wn[2 * c].z, an0);
      ar1 = SDOT4(h1.z, wr[2 * c + 1].z, ar1);
      az1 = SDOT4(h1.z, wz[2 * c + 1].z, az1);
      an1 = SDOT4(h1.z, wn[2 * c + 1].z, an1);
      ar0 = SDOT4(h0.w, wr[2 * c].w, ar0);
      az0 = SDOT4(h0.w, wz[2 * c].w, az0);
      an0 = SDOT4(h0.w, wn[2 * c].w, an0);
      ar1 = SDOT4(h1.w, wr[2 * c + 1].w, ar1);
      az1 = SDOT4(h1.w, wz[2 * c + 1].w, az1);
      an1 = SDOT4(h1.w, wn[2 * c + 1].w, an1);
    }
    const int ar = ar0 + ar1, az = az0 + az1, an = an0 + an1;

    // ---- C) beta + momentum + gates ----
    const float hWb = (float)__builtin_amdgcn_readlane(hwb_i, 63) * wbsc;
    const half2_t x2 = half2_t{(_Float16)xv.x, (_Float16)xv.y};
    xv = xg2[(t + 1 < TLEN) ? t + 1 : t];
    const float beta = fast_sigmoid(dot2acc(x2, wbx2, hWb + bbeta));
    vr = beta * vr + dot2acc(x2, wih_r, bih_r);
    vz = beta * vz + dot2acc(x2, wih_z, bih_z);
    vn = beta * vn + dot2acc(x2, wih_n, bih_n);

    const float r = fast_sigmoid(vr + (float)ar * sc_r + bhh_r);
    const float z = fast_sigmoid(vz + (float)az * sc_z + bhh_z);
    const float n = fast_tanh(vn + r * ((float)an * sc_n + bhh_n));
    h_old = (1.0f - z) * n + z * h_old;

    // ---- D) quantize h -> i8, one byte store per thread ----
    const int nxt = cur ^ 1;
    const int qb = (int)rintf(h_old * 127.0f);
    reinterpret_cast<unsigned char*>(hq[nxt])[tid] = (unsigned char)(qb & 0xff);

    if (tid == 0) betas[(size_t)b * TLEN + t] = beta;

    __syncthreads();
    cur = nxt;
  }

  // ---- head ----
  float hp = h_old * W_head[tid];
  hp = wave_sum63_f(hp);
  if (lane == 63) red[wv] = hp;
  __syncthreads();
  if (tid == 0) out[b] = red[0] + red[1] + red[2] + red[3] + b_head[0];
}

extern "C" void kernel_launch(void* const* d_in, const int* in_sizes, int n_in,
                              void* d_out, int out_size, void* d_ws, size_t ws_size,
                              hipStream_t stream) {
  const float* x      = (const float*)d_in[0];
  const float* W_ih   = (const float*)d_in[1];
  const float* W_hh   = (const float*)d_in[2];
  const float* b_ih   = (const float*)d_in[3];
  const float* b_hh   = (const float*)d_in[4];
  const float* Wb_x   = (const float*)d_in[5];
  const float* Wb_h   = (const float*)d_in[6];
  const float* b_beta = (const float*)d_in[7];
  const float* s      = (const float*)d_in[8];
  const float* W_head = (const float*)d_in[9];
  const float* b_head = (const float*)d_in[10];
  float* out = (float*)d_out;

  char* wsb = (char*)d_ws;
  uint4*    wq      = (uint4*)wsb;                 // 256*48*16 = 196608 B
  float*    scales  = (float*)(wsb + 196608);      // 768*4 = 3072 B
  unsigned* wbq     = (unsigned*)(wsb + 199680);   // 64*4 = 256 B
  float*    wbscale = (float*)(wsb + 199936);      // 4 B

  quant_whh<<<dim3(4), dim3(256), 0, stream>>>(W_hh, Wb_h, wq, scales, wbq, wbscale);
  momgru_persistent<<<dim3(BATCH), dim3(256), 0, stream>>>(
      x, W_ih, b_ih, b_hh, Wb_x, b_beta, s, W_head, b_head,
      (const uint4*)wq, (const float*)scales, (const unsigned*)wbq,
      (const float*)wbscale, out);
}